// Round 8
// baseline (327.680 us; speedup 1.0000x reference)
//
#include <hip/hip_runtime.h>

typedef unsigned short u16;
typedef u16 u16x4 __attribute__((ext_vector_type(4)));
typedef float f32x4 __attribute__((ext_vector_type(4)));
typedef __bf16 bf16x8 __attribute__((ext_vector_type(8)));

#define M_DIM 8192   // B*H = 4*2048
#define N_DIM 1024   // O
#define K_DIM 4096   // I*(D+1) = 1024*4
#define BM 256
#define BN 128
#define BK 32

__device__ __forceinline__ u16 f2bf(float f) {
  unsigned u = __float_as_uint(f);
  u += 0x7FFFu + ((u >> 16) & 1u);   // round-to-nearest-even
  return (u16)(u >> 16);
}

// ---- kernel 1: W2[o][i*4+d] = ws[o][i] * w[o][d], bf16 [N][K] ----
__global__ __launch_bounds__(256) void k_w2(const float* __restrict__ w,
                                            const float* __restrict__ ws,
                                            u16* __restrict__ w2) {
  int idx = blockIdx.x * 256 + threadIdx.x;  // idx = o*1024 + i
  int o = idx >> 10;
  float s = ws[idx];
  f32x4 wv = *(const f32x4*)(w + o * 4);
  u16x4 r;
  r[0] = f2bf(s * wv[0]); r[1] = f2bf(s * wv[1]);
  r[2] = f2bf(s * wv[2]); r[3] = f2bf(s * wv[3]);
  *(u16x4*)(w2 + (size_t)idx * 4) = r;
}

// ---- kernel 2: fused cvt+GEMM, counted-vmcnt 2-phase schedule, 48 KB LDS.
// BM=256 BN=128 BK=32, 8 waves (64x64 out each). A: fp32 global -> regs
// (2 named sets, 2-tile manual unroll, lifetime exactly 1 tile) -> cvt ->
// ds_write, double-buffered. B: bf16 via global_load_lds, 1 tile ahead.
// Swizzle: chunk = lc ^ ((row>>1)&3) -> 2-way bank alias = free (the R7
// (row&3) variant was a 4-way conflict, 8.4M cycles/dispatch).
// vmcnt NEVER drained in the loop: vmcnt(5) at ph0 (retire A(t+1) regs),
// vmcnt(4) at ph1 (retire B(t+1) gll16, keep A(t+2) in flight). ----
typedef __attribute__((address_space(1))) const void gvoid_t;
typedef __attribute__((address_space(3))) void lvoid_t;
__device__ __forceinline__ void gll16(const void* g, void* l) {
  __builtin_amdgcn_global_load_lds((gvoid_t*)g, (lvoid_t*)l, 16, 0, 0);
}

__global__ __launch_bounds__(512) void k_gemm(const float* __restrict__ A,
                                              const u16* __restrict__ Bt,
                                              float* __restrict__ C) {
  __shared__ u16 lds[24576];           // 48 KiB
  u16* const sA0 = lds;                // 2 x 16 KB (A: 256 x 32 bf16)
  u16* const sA1 = lds + 8192;
  u16* const sB0 = lds + 16384;        // 2 x 8 KB (B: 128 x 32 bf16)
  u16* const sB1 = lds + 20480;

  const int t    = threadIdx.x;
  const int lane = t & 63;
  const int wid  = t >> 6;           // 0..7

  // XCD swizzle: 256 blocks; xcd = L&7 owns m-panels 4x..4x+3, each with
  // its 8 n-blocks consecutive -> one XCD L2 (A panel fetched once).
  const int L   = blockIdx.x;
  const int xcd = L & 7;
  const int jb  = L >> 3;            // 0..31
  const int m0  = (xcd * 4 + (jb >> 3)) * BM;
  const int n0  = (jb & 7) * BN;

  // --- staging geometry: rows = 32 bf16 = 64 B = 4 x 16B chunks.
  // LDS slot s holds row r=s>>2, logical chunk cg=(s&3)^((r>>1)&3).
  // A: reg-staged (linear ds_write dest, source chunk cg).
  // B: gll16 (linear LDS dest, pre-swizzled global source). ---
  const int cg0 = (t & 3) ^ ((t >> 3) & 3);   // same for both A rows
  const int r0  = t >> 2;                      // A row 0..127
  const float* gA0 = A + (size_t)(m0 + r0) * K_DIM + cg0 * 8;
  const float* gA1 = A + (size_t)(m0 + 128 + r0) * K_DIM + cg0 * 8;
  const int lAd0 = t * 8;                      // u16 units (slot t)
  const int lAd1 = 4096 + t * 8;               // slot 512+t
  const u16* gB = Bt + (size_t)(n0 + r0) * K_DIM + cg0 * 8;
  const int dBo = t * 8;

  // wave tile 64x64: wave grid 4(M) x 2(N); 4x4 MFMA frags per K-tile
  const int wm = (wid >> 1) * 64;
  const int wn = (wid & 1) * 64;
  const int fr = lane & 15;
  const int lc = lane >> 4;

  // loop-invariant frag read offsets (u16 units), conflict-free swizzle
  int aoff[4], boff[4];
#pragma unroll
  for (int i = 0; i < 4; i++) {
    int ra = wm + i * 16 + fr;
    aoff[i] = ra * 32 + ((lc ^ ((ra >> 1) & 3)) << 3);
    int rb = wn + i * 16 + fr;
    boff[i] = rb * 32 + ((lc ^ ((rb >> 1) & 3)) << 3);
  }

  f32x4 acc[4][4];
#pragma unroll
  for (int i = 0; i < 4; i++)
#pragma unroll
    for (int j = 0; j < 4; j++) acc[i][j] = (f32x4){0.f, 0.f, 0.f, 0.f};

  f32x4 xa, xb, xc, xd;   // set X (A regs)
  f32x4 ya, yb, yc, yd;   // set Y

#define STORESET(bufA, pa, pb, pc, pd)                          \
  do {                                                          \
    bf16x8 v0, v1;                                              \
    v0[0] = (__bf16)pa[0]; v0[1] = (__bf16)pa[1];               \
    v0[2] = (__bf16)pa[2]; v0[3] = (__bf16)pa[3];               \
    v0[4] = (__bf16)pb[0]; v0[5] = (__bf16)pb[1];               \
    v0[6] = (__bf16)pb[2]; v0[7] = (__bf16)pb[3];               \
    v1[0] = (__bf16)pc[0]; v1[1] = (__bf16)pc[1];               \
    v1[2] = (__bf16)pc[2]; v1[3] = (__bf16)pc[3];               \
    v1[4] = (__bf16)pd[0]; v1[5] = (__bf16)pd[1];               \
    v1[6] = (__bf16)pd[2]; v1[7] = (__bf16)pd[3];               \
    *(bf16x8*)((bufA) + lAd0) = v0;                             \
    *(bf16x8*)((bufA) + lAd1) = v1;                             \
  } while (0)

  // TILE: pAc/pBc = compute buffers; pAn/pBs = stage targets.
  // la..ld = reg set to LOAD (A(t+2)); sa..sd = reg set to STORE (A(t+1)).
  // ka = fp32 col offset of tile t+2; kb = u16 col offset of tile t+1.
#define TILE(pAc, pBc, pAn, pBs, la, lb, lcr, ld, sa, sb, sc, sd, kb, ka)   \
  do {                                                                      \
    bf16x8 af0, af1, bq0, bq1, bq2, bq3;                                    \
    af0 = *(const bf16x8*)((pAc) + aoff[0]);                                \
    af1 = *(const bf16x8*)((pAc) + aoff[1]);                                \
    bq0 = *(const bf16x8*)((pBc) + boff[0]);                                \
    bq1 = *(const bf16x8*)((pBc) + boff[1]);                                \
    bq2 = *(const bf16x8*)((pBc) + boff[2]);                                \
    bq3 = *(const bf16x8*)((pBc) + boff[3]);                                \
    gll16(gB + (kb), (pBs) + dBo);                                          \
    la  = *(const f32x4*)(gA0 + (ka));                                      \
    lb  = *(const f32x4*)(gA0 + (ka) + 4);                                  \
    lcr = *(const f32x4*)(gA1 + (ka));                                      \
    ld  = *(const f32x4*)(gA1 + (ka) + 4);                                  \
    asm volatile("s_waitcnt vmcnt(5)" ::: "memory");                        \
    STORESET(pAn, sa, sb, sc, sd);                                          \
    __builtin_amdgcn_s_barrier();                                           \
    asm volatile("s_waitcnt lgkmcnt(0)" ::: "memory");                      \
    __builtin_amdgcn_s_setprio(1);                                          \
    _Pragma("unroll")                                                       \
    for (int n_ = 0; n_ < 4; n_++) {                                        \
      bf16x8 bz = n_ == 0 ? bq0 : n_ == 1 ? bq1 : n_ == 2 ? bq2 : bq3;      \
      acc[0][n_] = __builtin_amdgcn_mfma_f32_16x16x32_bf16(af0, bz,         \
                                                           acc[0][n_], 0, 0, 0); \
      acc[1][n_] = __builtin_amdgcn_mfma_f32_16x16x32_bf16(af1, bz,         \
                                                           acc[1][n_], 0, 0, 0); \
    }                                                                       \
    __builtin_amdgcn_s_setprio(0);                                          \
    __builtin_amdgcn_s_barrier();                                           \
    af0 = *(const bf16x8*)((pAc) + aoff[2]);                                \
    af1 = *(const bf16x8*)((pAc) + aoff[3]);                                \
    asm volatile("s_waitcnt vmcnt(4)" ::: "memory");                        \
    __builtin_amdgcn_s_barrier();                                           \
    asm volatile("s_waitcnt lgkmcnt(0)" ::: "memory");                      \
    __builtin_amdgcn_s_setprio(1);                                          \
    _Pragma("unroll")                                                       \
    for (int n_ = 0; n_ < 4; n_++) {                                        \
      bf16x8 bz = n_ == 0 ? bq0 : n_ == 1 ? bq1 : n_ == 2 ? bq2 : bq3;      \
      acc[2][n_] = __builtin_amdgcn_mfma_f32_16x16x32_bf16(af0, bz,         \
                                                           acc[2][n_], 0, 0, 0); \
      acc[3][n_] = __builtin_amdgcn_mfma_f32_16x16x32_bf16(af1, bz,         \
                                                           acc[3][n_], 0, 0, 0); \
    }                                                                       \
    __builtin_amdgcn_s_setprio(0);                                          \
    __builtin_amdgcn_s_barrier();                                           \
  } while (0)

  // ---- prologue ----
  xa = *(const f32x4*)(gA0);      xb = *(const f32x4*)(gA0 + 4);
  xc = *(const f32x4*)(gA1);      xd = *(const f32x4*)(gA1 + 4);
  asm volatile("s_waitcnt vmcnt(0)" ::: "memory");
  STORESET(sA0, xa, xb, xc, xd);               // A(0) -> sA0
  gll16(gB, sB0 + dBo);                        // B(0) -> sB0
  ya = *(const f32x4*)(gA0 + 32); yb = *(const f32x4*)(gA0 + 36);
  yc = *(const f32x4*)(gA1 + 32); yd = *(const f32x4*)(gA1 + 36);
  // queue: [B(0), A(1)x4] -> retire B(0), keep A(1) in flight
  asm volatile("s_waitcnt vmcnt(4) lgkmcnt(0)" ::: "memory");
  __builtin_amdgcn_s_barrier();

  // ---- main loop: 64 iters x 2 tiles; staging wraps at the end (junk
  // lands in buffers never read again — in-bounds, harmless) ----
  for (int it = 0; it < 64; ++it) {
    const int t0 = 2 * it;
    // even tile: read sA0/sB0, write sA1/sB1; load->X (A(t0+2)), store Y (A(t0+1))
    TILE(sA0, sB0, sA1, sB1, xa, xb, xc, xd, ya, yb, yc, yd,
         ((t0 + 1) & 127) * 32, ((t0 + 2) & 127) * 32);
    // odd tile: read sA1/sB1, write sA0/sB0; load->Y, store X
    TILE(sA1, sB1, sA0, sB0, ya, yb, yc, yd, xa, xb, xc, xd,
         ((t0 + 2) & 127) * 32, ((t0 + 3) & 127) * 32);
  }

#undef TILE
#undef STORESET

  // C/D layout: col = lane&15, row = (lane>>4)*4 + reg
  const int cr = (lane >> 4) * 4;
  const int cc = lane & 15;
#pragma unroll
  for (int mi = 0; mi < 4; mi++)
#pragma unroll
    for (int ni = 0; ni < 4; ni++) {
      float* cp = C + (size_t)(m0 + wm + mi * 16 + cr) * N_DIM +
                  (n0 + wn + ni * 16 + cc);
#pragma unroll
      for (int r = 0; r < 4; r++) cp[(size_t)r * N_DIM] = acc[mi][ni][r];
    }
}

extern "C" void kernel_launch(void* const* d_in, const int* in_sizes, int n_in,
                              void* d_out, int out_size, void* d_ws, size_t ws_size,
                              hipStream_t stream) {
  const float* x  = (const float*)d_in[0];   // (4,2048,1024,4) fp32
  const float* w  = (const float*)d_in[1];   // (1024,4) fp32
  const float* ws = (const float*)d_in[2];   // (1024,1024) fp32
  float* out = (float*)d_out;                // (4,2048,1024) fp32 = C[M][N]

  u16* w2 = (u16*)d_ws;                      // 4.2M u16 = 8 MB

  k_w2<<<4096, 256, 0, stream>>>(w, ws, w2);
  k_gemm<<<256, 512, 0, stream>>>(x, w2, out);
}

// Round 9
// 278.215 us; speedup vs baseline: 1.1778x; 1.1778x over previous
//
#include <hip/hip_runtime.h>

typedef unsigned short u16;
typedef u16 u16x4 __attribute__((ext_vector_type(4)));
typedef float f32x4 __attribute__((ext_vector_type(4)));
typedef __bf16 bf16x8 __attribute__((ext_vector_type(8)));

#define M_DIM 8192   // B*H = 4*2048
#define N_DIM 1024   // O
#define K_DIM 4096   // I*(D+1) = 1024*4
#define BM 256
#define BN 128
#define BK 32

__device__ __forceinline__ u16 f2bf(float f) {
  unsigned u = __float_as_uint(f);
  u += 0x7FFFu + ((u >> 16) & 1u);   // round-to-nearest-even
  return (u16)(u >> 16);
}

// ---- kernel 1: x fp32 -> bf16 (lane-contiguous 16B read / 8B write) ----
__global__ __launch_bounds__(256) void k_cvt(const float* __restrict__ x,
                                             u16* __restrict__ y) {
  long i = ((long)blockIdx.x * 256 + threadIdx.x) * 4;
  f32x4 a = *(const f32x4*)(x + i);
  u16x4 r;
  r[0] = f2bf(a[0]); r[1] = f2bf(a[1]); r[2] = f2bf(a[2]); r[3] = f2bf(a[3]);
  *(u16x4*)(y + i) = r;
}

// ---- kernel 2: W2[o][i*4+d] = ws[o][i] * w[o][d], bf16 [N][K] ----
__global__ __launch_bounds__(256) void k_w2(const float* __restrict__ w,
                                            const float* __restrict__ ws,
                                            u16* __restrict__ w2) {
  int idx = blockIdx.x * 256 + threadIdx.x;  // idx = o*1024 + i
  int o = idx >> 10;
  float s = ws[idx];
  f32x4 wv = *(const f32x4*)(w + o * 4);
  u16x4 r;
  r[0] = f2bf(s * wv[0]); r[1] = f2bf(s * wv[1]);
  r[2] = f2bf(s * wv[2]); r[3] = f2bf(s * wv[3]);
  *(u16x4*)(w2 + (size_t)idx * 4) = r;
}

// ---- kernel 3: bf16 GEMM, counted-vmcnt phase schedule, 64 KiB LDS.
// BM=256 BN=128 BK=32, 8 waves (64x64 out each), 2 phases per K-tile.
// A triple-buffered (staged 2 tiles ahead), B double-buffered (1 ahead),
// via global_load_lds (linear LDS dest, pre-swizzled global source).
// ONE counted vmcnt(2) per K-tile; never drained inside the loop.
// SWIZZLE (fixed vs R7): chunk = lc ^ ((row>>1)&3). The R7 variant
// lc ^ (row&3) put rows 4 apart on identical banks (4 rows/class in a
// 16-lane frag read -> 4-way conflict, 8.4M cycles/dispatch). With
// (row>>1)&3, same-class rows are 8 apart: 2 rows/class -> 2-way = free. ----
typedef __attribute__((address_space(1))) const void gvoid_t;
typedef __attribute__((address_space(3))) void lvoid_t;
__device__ __forceinline__ void gll16(const void* g, void* l) {
  __builtin_amdgcn_global_load_lds((gvoid_t*)g, (lvoid_t*)l, 16, 0, 0);
}

__global__ __launch_bounds__(512, 4) void k_gemm(const u16* __restrict__ A,
                                                 const u16* __restrict__ Bt,
                                                 float* __restrict__ C) {
  __shared__ u16 lds[32768];           // 64 KiB total
  u16* const sA0 = lds;                // 3 x 16 KB (A: 256 x 32 bf16)
  u16* const sA1 = lds + 8192;
  u16* const sA2 = lds + 16384;
  u16* const sB0 = lds + 24576;        // 2 x 8 KB (B: 128 x 32 bf16)
  u16* const sB1 = lds + 28672;

  const int t    = threadIdx.x;
  const int lane = t & 63;
  const int wid  = t >> 6;           // 0..7

  // XCD swizzle: 256 blocks; xcd = L&7 owns m-panels 4x..4x+3, each with
  // its 8 n-blocks consecutive -> one XCD L2 (A panel fetched once).
  const int L   = blockIdx.x;
  const int xcd = L & 7;
  const int jb  = L >> 3;            // 0..31
  const int m0  = (xcd * 4 + (jb >> 3)) * BM;
  const int n0  = (jb & 7) * BN;

  // --- staging geometry: rows are 32 bf16 = 64 B = 4 x 16B chunks.
  // LDS slot s (16B) holds row r=s>>2, logical chunk cg=(s&3)^((r>>1)&3).
  // gll16 dest is linear in s (base + lane*16); swizzle lives in the
  // pre-swizzled global source address. ---
  const u16* gA0; const u16* gA1; int dA0, dA1;
  {
    int s = t,       r = s >> 2, cg = (s & 3) ^ ((r >> 1) & 3);
    gA0 = A + (size_t)(m0 + r) * K_DIM + cg * 8;  dA0 = s * 8;
    s = 512 + t;     r = s >> 2; cg = (s & 3) ^ ((r >> 1) & 3);
    gA1 = A + (size_t)(m0 + r) * K_DIM + cg * 8;  dA1 = s * 8;
  }
  const u16* gB; int dBo;
  {
    int s = t, r = s >> 2, cg = (s & 3) ^ ((r >> 1) & 3);
    gB = Bt + (size_t)(n0 + r) * K_DIM + cg * 8;  dBo = s * 8;
  }

  // wave tile 64x64: wave grid 4(M) x 2(N); 4x4 MFMA frags per K-tile
  const int wm = (wid >> 1) * 64;
  const int wn = (wid & 1) * 64;
  const int fr = lane & 15;
  const int lc = lane >> 4;          // 16B chunk within the 32-wide K-tile

  f32x4 acc[4][4];
#pragma unroll
  for (int i = 0; i < 4; i++)
#pragma unroll
    for (int j = 0; j < 4; j++) acc[i][j] = (f32x4){0.f, 0.f, 0.f, 0.f};

  // ---- prologue: A(0)x2, B(0)x1, A(1)x2; leave A(1) in flight ----
  gll16(gA0, sA0 + dA0); gll16(gA1, sA0 + dA1);
  gll16(gB,  sB0 + dBo);
  gll16(gA0 + 32, sA1 + dA0); gll16(gA1 + 32, sA1 + dA1);
  asm volatile("s_waitcnt vmcnt(2)" ::: "memory");
  __builtin_amdgcn_s_barrier();

  u16 *pAc = sA0, *pAn = sA1, *pAs = sA2;
  u16 *pBc = sB0, *pBs = sB1;

#define AREAD(dst, MI)                                                     \
  do {                                                                     \
    int r_ = wm + (MI) * 16 + fr;                                          \
    dst = *(const bf16x8*)(pAc + r_ * 32 + ((lc ^ ((r_ >> 1) & 3)) * 8));  \
  } while (0)

  // ---- main loop: 128 K-tiles x 2 phases; staging wraps (junk lands in
  // buffers never read again — in-bounds, harmless) ----
  for (int tt = 0; tt < 128; ++tt) {
    const int ka = ((tt + 2) & 127) * BK;   // A staged 2 tiles ahead
    const int kb = ((tt + 1) & 127) * BK;   // B staged 1 tile ahead
    bf16x8 af0, af1, bq[4];

    // ---- ph0: A frags mi0-1 + all B frags; stage B(t+1) ----
    AREAD(af0, 0); AREAD(af1, 1);
#pragma unroll
    for (int n_ = 0; n_ < 4; n_++) {
      int r_ = wn + n_ * 16 + fr;
      bq[n_] = *(const bf16x8*)(pBc + r_ * 32 + ((lc ^ ((r_ >> 1) & 3)) * 8));
    }
    gll16(gB + kb, pBs + dBo);
    __builtin_amdgcn_s_barrier();
    asm volatile("s_waitcnt lgkmcnt(0)" ::: "memory");
    __builtin_amdgcn_s_setprio(1);
#pragma unroll
    for (int n_ = 0; n_ < 4; n_++) {
      acc[0][n_] = __builtin_amdgcn_mfma_f32_16x16x32_bf16(af0, bq[n_],
                                                           acc[0][n_], 0, 0, 0);
      acc[1][n_] = __builtin_amdgcn_mfma_f32_16x16x32_bf16(af1, bq[n_],
                                                           acc[1][n_], 0, 0, 0);
    }
    __builtin_amdgcn_s_setprio(0);
    __builtin_amdgcn_s_barrier();

    // ---- ph1: A frags mi2-3; stage A(t+2); counted vmcnt ----
    AREAD(af0, 2); AREAD(af1, 3);
    gll16(gA0 + ka, pAs + dA0); gll16(gA1 + ka, pAs + dA1);
    // queue (oldest first): A(t+1)x2, B(t+1)x1, A(t+2)x2 -> retire 3,
    // keep A(t+2) in flight: tile t+1 is ready, lookahead preserved.
    asm volatile("s_waitcnt vmcnt(2)" ::: "memory");
    __builtin_amdgcn_s_barrier();
    asm volatile("s_waitcnt lgkmcnt(0)" ::: "memory");
    __builtin_amdgcn_s_setprio(1);
#pragma unroll
    for (int n_ = 0; n_ < 4; n_++) {
      acc[2][n_] = __builtin_amdgcn_mfma_f32_16x16x32_bf16(af0, bq[n_],
                                                           acc[2][n_], 0, 0, 0);
      acc[3][n_] = __builtin_amdgcn_mfma_f32_16x16x32_bf16(af1, bq[n_],
                                                           acc[3][n_], 0, 0, 0);
    }
    __builtin_amdgcn_s_setprio(0);
    __builtin_amdgcn_s_barrier();

    // rotate buffers: A period-3, B period-2
    u16* tmp = pAc; pAc = pAn; pAn = pAs; pAs = tmp;
    tmp = pBc; pBc = pBs; pBs = tmp;
  }

#undef AREAD

  // C/D layout: col = lane&15, row = (lane>>4)*4 + reg
  const int cr = (lane >> 4) * 4;
  const int cc = lane & 15;
#pragma unroll
  for (int mi = 0; mi < 4; mi++)
#pragma unroll
    for (int ni = 0; ni < 4; ni++) {
      float* cp = C + (size_t)(m0 + wm + mi * 16 + cr) * N_DIM +
                  (n0 + wn + ni * 16 + cc);
#pragma unroll
      for (int r = 0; r < 4; r++) cp[(size_t)r * N_DIM] = acc[mi][ni][r];
    }
}

extern "C" void kernel_launch(void* const* d_in, const int* in_sizes, int n_in,
                              void* d_out, int out_size, void* d_ws, size_t ws_size,
                              hipStream_t stream) {
  const float* x  = (const float*)d_in[0];   // (4,2048,1024,4) fp32
  const float* w  = (const float*)d_in[1];   // (1024,4) fp32
  const float* ws = (const float*)d_in[2];   // (1024,1024) fp32
  float* out = (float*)d_out;                // (4,2048,1024) fp32 = C[M][N]

  u16* xbf = (u16*)d_ws;                         // 33.5M u16 = 64 MB
  u16* w2  = xbf + (size_t)M_DIM * K_DIM;        // 4.2M u16 = 8 MB

  k_cvt<<<32768, 256, 0, stream>>>(x, xbf);
  k_w2<<<4096, 256, 0, stream>>>(w, ws, w2);
  k_gemm<<<256, 512, 0, stream>>>(xbf, w2, out);
}